// Round 2
// baseline (535.254 us; speedup 1.0000x reference)
//
#include <hip/hip_runtime.h>
#include <math.h>

#define L 8
#define P 8
#define S 128
#define B 16
#define W 768
#define M 64

#define LPB (L * P * B)     // 1024
#define W4 (W / 4)          // 192 float4 lanes

// ---------------------------------------------------------------------------
// Kernel 1: single pass over embeds.
// One block per (l,p,b) = blk in [0, 1024). 192 threads, thread t owns
// float4 lane [4t, 4t+4) of W. Computes:
//   acc_w  = sum_s w1[s] * e[l,p,s,b,w]            (per-thread float4)
//   mp_w   = max_s e[l,p,s,b,w]                    -> ws
//   score_raw[blk] = sum_w w0[w] * acc_w           (block reduction)
// ---------------------------------------------------------------------------
__global__ __launch_bounds__(W4) void k1_pass(
    const float* __restrict__ embeds,
    const float* __restrict__ w1,
    const float* __restrict__ w0,
    float* __restrict__ mp_out,      // [LPB * W]
    float* __restrict__ score_raw)   // [LPB]
{
    const int blk = blockIdx.x;          // (l*P+p)*B + b
    const int t   = threadIdx.x;         // 0..191
    const int lp  = blk / B;
    const int b   = blk % B;

    __shared__ float lw1[S];
    if (t < S) lw1[t] = w1[t];
    __syncthreads();

    const float* base = embeds + (size_t)lp * S * B * W + (size_t)b * W + 4 * t;

    float4 acc = make_float4(0.f, 0.f, 0.f, 0.f);
    float4 mp  = make_float4(-INFINITY, -INFINITY, -INFINITY, -INFINITY);

#pragma unroll 8
    for (int s = 0; s < S; ++s) {
        const float4 v = *reinterpret_cast<const float4*>(base + (size_t)s * B * W);
        const float c = lw1[s];
        acc.x = fmaf(c, v.x, acc.x);
        acc.y = fmaf(c, v.y, acc.y);
        acc.z = fmaf(c, v.z, acc.z);
        acc.w = fmaf(c, v.w, acc.w);
        mp.x = fmaxf(mp.x, v.x);
        mp.y = fmaxf(mp.y, v.y);
        mp.z = fmaxf(mp.z, v.z);
        mp.w = fmaxf(mp.w, v.w);
    }

    // store max-pool result: layout [lpb][w]
    *reinterpret_cast<float4*>(mp_out + (size_t)blk * W + 4 * t) = mp;

    // per-thread partial of sum_w w0[w]*acc[w]
    const float4 w0v = *reinterpret_cast<const float4*>(w0 + 4 * t);
    float part = w0v.x * acc.x + w0v.y * acc.y + w0v.z * acc.z + w0v.w * acc.w;

    // 64-lane wave reduce, then 3 waves via LDS
#pragma unroll
    for (int off = 32; off > 0; off >>= 1)
        part += __shfl_down(part, off, 64);

    __shared__ float wred[3];
    if ((t & 63) == 0) wred[t >> 6] = part;
    __syncthreads();
    if (t == 0) score_raw[blk] = wred[0] + wred[1] + wred[2];
}

// ---------------------------------------------------------------------------
// Kernel 2: score[l,p,b] = softmax_P( sigmoid(score_raw + b0*sum(w1) + b1) )
// 128 threads total, one per (l,b).
// ---------------------------------------------------------------------------
__global__ __launch_bounds__(128) void k2_softmax(
    const float* __restrict__ score_raw,  // [LPB]
    const float* __restrict__ w1,
    const float* __restrict__ b0,
    const float* __restrict__ b1,
    float* __restrict__ score)            // [LPB]
{
    const int idx = threadIdx.x;   // 0..127 = l*B + b
    const int l = idx / B;
    const int b = idx % B;

    float sw1 = 0.f;
#pragma unroll
    for (int s = 0; s < S; ++s) sw1 += w1[s];
    const float bias = b0[0] * sw1 + b1[0];

    float sc[P];
    float mx = -INFINITY;
#pragma unroll
    for (int p = 0; p < P; ++p) {
        const float raw = score_raw[(l * P + p) * B + b] + bias;
        sc[p] = 1.f / (1.f + expf(-raw));   // sigmoid
        mx = fmaxf(mx, sc[p]);
    }
    float sum = 0.f;
#pragma unroll
    for (int p = 0; p < P; ++p) {
        sc[p] = expf(sc[p] - mx);
        sum += sc[p];
    }
    const float inv = 1.f / sum;
#pragma unroll
    for (int p = 0; p < P; ++p)
        score[(l * P + p) * B + b] = sc[p] * inv;
}

// ---------------------------------------------------------------------------
// Kernel 3: sem[l,b,w] = sum_p score[l,p,b] * mp[l,p,b,w]
// One thread per (l,b,w): L*B*W = 98304 threads.
// ---------------------------------------------------------------------------
__global__ __launch_bounds__(256) void k3_weighted_sum(
    const float* __restrict__ mp,     // [LPB * W]
    const float* __restrict__ score,  // [LPB]
    float* __restrict__ sem)          // [L*B*W]
{
    const int idx = blockIdx.x * 256 + threadIdx.x;
    if (idx >= L * B * W) return;
    const int w  = idx % W;
    const int lb = idx / W;
    const int l  = lb / B;
    const int b  = lb % B;

    float acc = 0.f;
#pragma unroll
    for (int p = 0; p < P; ++p) {
        const int lpb = (l * P + p) * B + b;
        acc = fmaf(score[lpb], mp[(size_t)lpb * W + w], acc);
    }
    sem[(size_t)(l * B + b) * W + w] = acc;
}

// ---------------------------------------------------------------------------
// Kernel 4: out[b,m,w] = sum_l mask[b,l,m] * sem[l,b,w]
// One thread per (b,m,w): B*M*W = 786432 threads.
// ---------------------------------------------------------------------------
__global__ __launch_bounds__(256) void k4_mask_contract(
    const float* __restrict__ mask,   // [B*L*M]
    const float* __restrict__ sem,    // [L*B*W]
    float* __restrict__ out)          // [B*M*W]
{
    const int idx = blockIdx.x * 256 + threadIdx.x;
    if (idx >= B * M * W) return;
    const int w  = idx % W;
    const int bm = idx / W;
    const int m  = bm % M;
    const int b  = bm / M;

    float acc = 0.f;
#pragma unroll
    for (int l = 0; l < L; ++l)
        acc = fmaf(mask[(b * L + l) * M + m], sem[(size_t)(l * B + b) * W + w], acc);
    out[idx] = acc;
}

// ---------------------------------------------------------------------------
extern "C" void kernel_launch(void* const* d_in, const int* in_sizes, int n_in,
                              void* d_out, int out_size, void* d_ws, size_t ws_size,
                              hipStream_t stream) {
    const float* embeds = (const float*)d_in[0];
    const float* mask   = (const float*)d_in[1];
    const float* w0     = (const float*)d_in[2];
    const float* b0     = (const float*)d_in[3];
    const float* w1     = (const float*)d_in[4];
    const float* b1     = (const float*)d_in[5];
    float* out = (float*)d_out;

    float* ws        = (float*)d_ws;
    float* mp        = ws;                       // LPB*W = 786432 floats
    float* score_raw = mp + (size_t)LPB * W;     // 1024
    float* score     = score_raw + LPB;          // 1024
    float* sem       = score + LPB;              // L*B*W = 98304

    k1_pass<<<LPB, W4, 0, stream>>>(embeds, w1, w0, mp, score_raw);
    k2_softmax<<<1, 128, 0, stream>>>(score_raw, w1, b0, b1, score);
    k3_weighted_sum<<<(L * B * W + 255) / 256, 256, 0, stream>>>(mp, score, sem);
    k4_mask_contract<<<(B * M * W + 255) / 256, 256, 0, stream>>>(mask, sem, out);
}

// Round 3
// 531.619 us; speedup vs baseline: 1.0068x; 1.0068x over previous
//
#include <hip/hip_runtime.h>
#include <math.h>

#define L 8
#define P 8
#define S 128
#define B 16
#define W 768
#define M 64

#define LPB (L * P * B)     // 1024
#define W4 (W / 4)          // 192 float4 lanes
#define NSH 4               // S-split factor
#define SH (S / NSH)        // 32 rows per chunk

// ---------------------------------------------------------------------------
// Kernel 1: partial pass over embeds. Grid = NSH * LPB = 4096 blocks.
// Block bid: sh = bid / LPB, lpb = bid % LPB (consecutive blocks share sh so
// the 16 b-blocks of one (lp,s) row stream a contiguous 48 KB line-set).
// Computes, over s in [sh*SH, (sh+1)*SH):
//   acc_w  = sum_s w1[s] * e[..]   -> score_part[sh][lpb] (block reduction)
//   mp_w   = max_s  e[..]          -> mp_part[sh][lpb][w]
// ---------------------------------------------------------------------------
__global__ __launch_bounds__(W4) void k1_pass(
    const float* __restrict__ embeds,
    const float* __restrict__ w1,
    const float* __restrict__ w0,
    float* __restrict__ mp_part,      // [NSH][LPB][W]
    float* __restrict__ score_part)   // [NSH][LPB]
{
    const int bid = blockIdx.x;
    const int sh  = bid / LPB;
    const int lpb = bid % LPB;
    const int t   = threadIdx.x;         // 0..191
    const int lp  = lpb / B;
    const int b   = lpb % B;

    __shared__ float lw1[SH];
    if (t < SH) lw1[t] = w1[sh * SH + t];
    __syncthreads();

    const float* base = embeds + (size_t)lp * S * B * W
                               + (size_t)(sh * SH) * B * W
                               + (size_t)b * W + 4 * t;

    float4 acc = make_float4(0.f, 0.f, 0.f, 0.f);
    float4 mp  = make_float4(-INFINITY, -INFINITY, -INFINITY, -INFINITY);

#pragma unroll 8
    for (int s = 0; s < SH; ++s) {
        const float4 v = *reinterpret_cast<const float4*>(base + (size_t)s * B * W);
        const float c = lw1[s];
        acc.x = fmaf(c, v.x, acc.x);
        acc.y = fmaf(c, v.y, acc.y);
        acc.z = fmaf(c, v.z, acc.z);
        acc.w = fmaf(c, v.w, acc.w);
        mp.x = fmaxf(mp.x, v.x);
        mp.y = fmaxf(mp.y, v.y);
        mp.z = fmaxf(mp.z, v.z);
        mp.w = fmaxf(mp.w, v.w);
    }

    *reinterpret_cast<float4*>(mp_part + ((size_t)sh * LPB + lpb) * W + 4 * t) = mp;

    const float4 w0v = *reinterpret_cast<const float4*>(w0 + 4 * t);
    float part = w0v.x * acc.x + w0v.y * acc.y + w0v.z * acc.z + w0v.w * acc.w;

#pragma unroll
    for (int off = 32; off > 0; off >>= 1)
        part += __shfl_down(part, off, 64);

    __shared__ float wred[3];
    if ((t & 63) == 0) wred[t >> 6] = part;
    __syncthreads();
    if (t == 0) score_part[(size_t)sh * LPB + lpb] = wred[0] + wred[1] + wred[2];
}

// ---------------------------------------------------------------------------
// Kernel 2: combine score partials; score = softmax_P(sigmoid(raw + bias))
// 128 threads, one per (l,b).
// ---------------------------------------------------------------------------
__global__ __launch_bounds__(128) void k2_softmax(
    const float* __restrict__ score_part,  // [NSH][LPB]
    const float* __restrict__ w1,
    const float* __restrict__ b0,
    const float* __restrict__ b1,
    float* __restrict__ score)             // [LPB]
{
    const int idx = threadIdx.x;   // l*B + b
    const int l = idx / B;
    const int b = idx % B;

    float sw1 = 0.f;
#pragma unroll
    for (int s = 0; s < S; ++s) sw1 += w1[s];
    const float bias = b0[0] * sw1 + b1[0];

    float sc[P];
    float mx = -INFINITY;
#pragma unroll
    for (int p = 0; p < P; ++p) {
        const int lpb = (l * P + p) * B + b;
        float raw = bias;
#pragma unroll
        for (int sh = 0; sh < NSH; ++sh) raw += score_part[sh * LPB + lpb];
        sc[p] = 1.f / (1.f + expf(-raw));   // sigmoid
        mx = fmaxf(mx, sc[p]);
    }
    float sum = 0.f;
#pragma unroll
    for (int p = 0; p < P; ++p) {
        sc[p] = expf(sc[p] - mx);
        sum += sc[p];
    }
    const float inv = 1.f / sum;
#pragma unroll
    for (int p = 0; p < P; ++p)
        score[(l * P + p) * B + b] = sc[p] * inv;
}

// ---------------------------------------------------------------------------
// Kernel 3: sem[l,b,w] = sum_p score[l,p,b] * max_sh mp_part[sh][l,p,b][w]
// One thread per (l,b,w).
// ---------------------------------------------------------------------------
__global__ __launch_bounds__(256) void k3_weighted_sum(
    const float* __restrict__ mp_part,  // [NSH][LPB][W]
    const float* __restrict__ score,    // [LPB]
    float* __restrict__ sem)            // [L*B*W]
{
    const int idx = blockIdx.x * 256 + threadIdx.x;
    if (idx >= L * B * W) return;
    const int w  = idx % W;
    const int lb = idx / W;
    const int l  = lb / B;
    const int b  = lb % B;

    float acc = 0.f;
#pragma unroll
    for (int p = 0; p < P; ++p) {
        const int lpb = (l * P + p) * B + b;
        float mp = -INFINITY;
#pragma unroll
        for (int sh = 0; sh < NSH; ++sh)
            mp = fmaxf(mp, mp_part[((size_t)sh * LPB + lpb) * W + w]);
        acc = fmaf(score[lpb], mp, acc);
    }
    sem[(size_t)(l * B + b) * W + w] = acc;
}

// ---------------------------------------------------------------------------
// Kernel 4: out[b,m,w] = sum_l mask[b,l,m] * sem[l,b,w]
// ---------------------------------------------------------------------------
__global__ __launch_bounds__(256) void k4_mask_contract(
    const float* __restrict__ mask,   // [B*L*M]
    const float* __restrict__ sem,    // [L*B*W]
    float* __restrict__ out)          // [B*M*W]
{
    const int idx = blockIdx.x * 256 + threadIdx.x;
    if (idx >= B * M * W) return;
    const int w  = idx % W;
    const int bm = idx / W;
    const int m  = bm % M;
    const int b  = bm / M;

    float acc = 0.f;
#pragma unroll
    for (int l = 0; l < L; ++l)
        acc = fmaf(mask[(b * L + l) * M + m], sem[(size_t)(l * B + b) * W + w], acc);
    out[idx] = acc;
}

// ---------------------------------------------------------------------------
extern "C" void kernel_launch(void* const* d_in, const int* in_sizes, int n_in,
                              void* d_out, int out_size, void* d_ws, size_t ws_size,
                              hipStream_t stream) {
    const float* embeds = (const float*)d_in[0];
    const float* mask   = (const float*)d_in[1];
    const float* w0     = (const float*)d_in[2];
    const float* b0     = (const float*)d_in[3];
    const float* w1     = (const float*)d_in[4];
    const float* b1     = (const float*)d_in[5];
    float* out = (float*)d_out;

    float* ws         = (float*)d_ws;
    float* mp_part    = ws;                                  // NSH*LPB*W floats
    float* score_part = mp_part + (size_t)NSH * LPB * W;     // NSH*LPB
    float* score      = score_part + (size_t)NSH * LPB;      // LPB
    float* sem        = score + LPB;                         // L*B*W

    k1_pass<<<NSH * LPB, W4, 0, stream>>>(embeds, w1, w0, mp_part, score_part);
    k2_softmax<<<1, 128, 0, stream>>>(score_part, w1, b0, b1, score);
    k3_weighted_sum<<<(L * B * W + 255) / 256, 256, 0, stream>>>(mp_part, score, sem);
    k4_mask_contract<<<(B * M * W + 255) / 256, 256, 0, stream>>>(mask, sem, out);
}